// Round 1
// baseline (539.917 us; speedup 1.0000x reference)
//
#include <hip/hip_runtime.h>
#include <hip/hip_bf16.h>

// Problem constants
#define NB 4
#define NS 2048
#define ND 512
#define NH 8
#define NM 4
#define NR 32
#define NHD 64

typedef short frag_ab __attribute__((ext_vector_type(8)));   // 8 bf16 (bits)
typedef float frag_cd __attribute__((ext_vector_type(4)));   // 4 f32

__device__ __forceinline__ float bf2f(short s) {
    union { unsigned u; float f; } c;
    c.u = ((unsigned)(unsigned short)s) << 16;
    return c.f;
}
__device__ __forceinline__ short f2bf(float f) {
    __hip_bfloat16 h = __float2bfloat16(f);
    union { __hip_bfloat16 h; short s; } c;
    c.h = h;
    return c.s;
}

// ---------------- cast f32 -> bf16, 8 elems/thread ----------------
__global__ void __launch_bounds__(256) k_cast(const float* __restrict__ in,
                                              short* __restrict__ out, int n8) {
    int i = blockIdx.x * 256 + threadIdx.x;
    if (i >= n8) return;
    const float4* p = (const float4*)in + (size_t)i * 2;
    float4 a = p[0], b = p[1];
    frag_ab o;
    o[0] = f2bf(a.x); o[1] = f2bf(a.y); o[2] = f2bf(a.z); o[3] = f2bf(a.w);
    o[4] = f2bf(b.x); o[5] = f2bf(b.y); o[6] = f2bf(b.z); o[7] = f2bf(b.w);
    ((frag_ab*)out)[i] = o;
}

// ---------- transpose-cast masks: in[m][r][s] f32 -> out[m][s][r] bf16 ----------
__global__ void __launch_bounds__(256) k_tcast_mask(const float* __restrict__ in,
                                                    short* __restrict__ out) {
    int m = blockIdx.y, s0 = blockIdx.x * 64, tid = threadIdx.x;
    __shared__ float tile[32][65];
    int c = tid & 63, r4 = tid >> 6;
#pragma unroll
    for (int p = 0; p < 8; ++p) {
        int r = p * 4 + r4;
        tile[r][c] = in[(m * 32 + r) * NS + s0 + c];
    }
    __syncthreads();
    int r = tid & 31, s4 = tid >> 5;
#pragma unroll
    for (int p = 0; p < 8; ++p) {
        int s = p * 8 + s4;
        out[(m * NS + s0 + s) * NR + r] = f2bf(tile[r][s]);
    }
}

// ---------------- lm[m][s][t] = sum_r m1t[m][s][r]*m2t[m][t][r] (K=32, 1 MFMA step) --------
__global__ void __launch_bounds__(64) k_lm(const short* __restrict__ m1t,
                                           const short* __restrict__ m2t,
                                           short* __restrict__ lm) {
    int tb = blockIdx.x * 64, sb = blockIdx.y * 64, m = blockIdx.z;
    int lane = threadIdx.x;
    int lo = lane & 15, g = lane >> 4;
    frag_ab a[4], b[4];
#pragma unroll
    for (int i = 0; i < 4; ++i) {
        a[i] = *(const frag_ab*)(m1t + (m * NS + sb + i * 16 + lo) * NR + g * 8);
        b[i] = *(const frag_ab*)(m2t + (m * NS + tb + i * 16 + lo) * NR + g * 8);
    }
#pragma unroll
    for (int mi = 0; mi < 4; ++mi)
#pragma unroll
        for (int ni = 0; ni < 4; ++ni) {
            frag_cd z = {0.f, 0.f, 0.f, 0.f};
            frag_cd d = __builtin_amdgcn_mfma_f32_16x16x32_bf16(a[mi], b[ni], z, 0, 0, 0);
#pragma unroll
            for (int r = 0; r < 4; ++r) {
                int srow = sb + mi * 16 + g * 4 + r;
                int tcol = tb + ni * 16 + lo;
                lm[(size_t)(m * NS + srow) * NS + tcol] = f2bf(d[r]);
            }
        }
}

// ---------------- lmr[m][s][t] = lm[m][s][roll[s][t]] ----------------
__global__ void __launch_bounds__(256) k_roll(const short* __restrict__ lm,
                                              const int* __restrict__ roll,
                                              short* __restrict__ lmr) {
    int bid = blockIdx.x;
    int m = bid & 3, s = bid >> 2;
    __shared__ __align__(16) short row[NS];
    int tid = threadIdx.x;
    size_t base = (size_t)(m * NS + s) * NS;
    *(frag_ab*)(row + tid * 8) = *(const frag_ab*)(lm + base + tid * 8);
    __syncthreads();
    const int* rrow = roll + (size_t)s * NS;
#pragma unroll
    for (int k = 0; k < 8; ++k) {
        int t = k * 256 + tid;
        lmr[base + t] = row[rrow[t]];
    }
}

// ---------------- generic bf16 MFMA GEMM: C[8192x512] = A * W^T + bias ----------------
// MODE 0: out bf16 at [b,h,s,d] (Q/K); MODE 1: out bf16 at [b,h,d,s] (V transposed);
// MODE 2: out f32 flat [row*512+col]
template <int MODE>
__global__ void __launch_bounds__(256) k_gemm(const short* __restrict__ A,
                                              const short* __restrict__ W,
                                              const float* __restrict__ bias,
                                              void* __restrict__ out) {
    int bn0 = blockIdx.x * 64, bm0 = blockIdx.y * 128;
    int wid = threadIdx.x >> 6, lane = threadIdx.x & 63;
    int lo = lane & 15, g = lane >> 4;
    int row0 = bm0 + wid * 32;
    frag_cd acc[2][4];
#pragma unroll
    for (int mi = 0; mi < 2; ++mi)
#pragma unroll
        for (int ni = 0; ni < 4; ++ni) acc[mi][ni] = (frag_cd){0.f, 0.f, 0.f, 0.f};
#pragma unroll
    for (int kk = 0; kk < 16; ++kk) {
        frag_ab af[2], bf[4];
#pragma unroll
        for (int mi = 0; mi < 2; ++mi)
            af[mi] = *(const frag_ab*)(A + (size_t)(row0 + mi * 16 + lo) * ND + kk * 32 + g * 8);
#pragma unroll
        for (int ni = 0; ni < 4; ++ni)
            bf[ni] = *(const frag_ab*)(W + (size_t)(bn0 + ni * 16 + lo) * ND + kk * 32 + g * 8);
#pragma unroll
        for (int mi = 0; mi < 2; ++mi)
#pragma unroll
            for (int ni = 0; ni < 4; ++ni)
                acc[mi][ni] = __builtin_amdgcn_mfma_f32_16x16x32_bf16(af[mi], bf[ni], acc[mi][ni], 0, 0, 0);
    }
#pragma unroll
    for (int mi = 0; mi < 2; ++mi)
#pragma unroll
        for (int ni = 0; ni < 4; ++ni)
#pragma unroll
            for (int r = 0; r < 4; ++r) {
                int row = row0 + mi * 16 + g * 4 + r;
                int col = bn0 + ni * 16 + lo;
                float v = acc[mi][ni][r] + bias[col];
                int b = row >> 11, s = row & 2047, h = col >> 6, d = col & 63;
                if (MODE == 0) {
                    ((short*)out)[(((size_t)(b * NH + h) * NS + s) << 6) + d] = f2bf(v);
                } else if (MODE == 1) {
                    ((short*)out)[((size_t)(b * NH + h) * NHD + d) * NS + s] = f2bf(v);
                } else {
                    ((float*)out)[(size_t)row * ND + col] = v;
                }
            }
}

// ---------------- fused attention: O_unnorm = (QK^T/8 * lm_rolled) @ V ; sumsq accum ----
__global__ void __launch_bounds__(256) k_attn(const short* __restrict__ Qb,
                                              const short* __restrict__ Kb,
                                              const short* __restrict__ Vt,
                                              const short* __restrict__ lmr,
                                              short* __restrict__ O,
                                              float* __restrict__ fro) {
    int sb = blockIdx.x;   // 0..31  (s-block of 64 rows)
    int h = blockIdx.y, b = blockIdx.z;
    int w = threadIdx.x >> 6, lane = threadIdx.x & 63;
    int lo = lane & 15, g = lane >> 4;
    int bh = b * NH + h;
    int m = h & 3;
    int srow = sb * 64 + w * 16;   // wave's 16-row s-base

    __shared__ __align__(16) short plds[4][1024];  // 2KB per wave, wave-private
    char* pbase = (char*)&plds[w][0];

    const short* qptr = Qb + ((size_t)bh * NS + srow + lo) * NHD + g * 8;
    frag_ab qf[2];
    qf[0] = *(const frag_ab*)(qptr);
    qf[1] = *(const frag_ab*)(qptr + 32);

    frag_cd acco[4];
#pragma unroll
    for (int ni = 0; ni < 4; ++ni) acco[ni] = (frag_cd){0.f, 0.f, 0.f, 0.f};
    float sumsq = 0.f;

    const short* kbase = Kb + (size_t)bh * NS * NHD;
    const short* vbase = Vt + (size_t)bh * NHD * NS;
    const short* lmbase = lmr + ((size_t)m * NS + srow + lo) * NS;  // per-lane A-layout row

    for (int tb = 0; tb < 32; ++tb) {
        int t0 = tb * 64;
        frag_cd sacc[4];
#pragma unroll
        for (int ni = 0; ni < 4; ++ni) sacc[ni] = (frag_cd){0.f, 0.f, 0.f, 0.f};
#pragma unroll
        for (int kk = 0; kk < 2; ++kk)
#pragma unroll
            for (int ni = 0; ni < 4; ++ni) {
                frag_ab kf = *(const frag_ab*)(kbase + (size_t)(t0 + ni * 16 + lo) * NHD + kk * 32 + g * 8);
                sacc[ni] = __builtin_amdgcn_mfma_f32_16x16x32_bf16(qf[kk], kf, sacc[ni], 0, 0, 0);
            }
        // scores (D-layout) -> wave-private LDS, XOR-swizzled rows
#pragma unroll
        for (int ni = 0; ni < 4; ++ni)
#pragma unroll
            for (int r = 0; r < 4; ++r) {
                int rs = g * 4 + r;
                int ct = ni * 16 + lo;
                int byte = (rs * 128 + ct * 2) ^ ((rs & 7) << 4);
                *(short*)(pbase + byte) = f2bf(sacc[ni][r]);
            }
        // read back in A-layout, multiply lm * 1/8, accumulate sumsq, pack bf16
        frag_ab pf[2];
#pragma unroll
        for (int kk = 0; kk < 2; ++kk) {
            int rbyte = (lo * 128 + kk * 64 + g * 16) ^ ((lo & 7) << 4);
            frag_ab sf = *(const frag_ab*)(pbase + rbyte);
            frag_ab lf = *(const frag_ab*)(lmbase + t0 + kk * 32 + g * 8);
            frag_ab pp;
#pragma unroll
            for (int j = 0; j < 8; ++j) {
                float p = bf2f(sf[j]) * bf2f(lf[j]) * 0.125f;
                sumsq += p * p;
                pp[j] = f2bf(p);
            }
            pf[kk] = pp;
        }
        // PV
#pragma unroll
        for (int ni = 0; ni < 4; ++ni)
#pragma unroll
            for (int kk = 0; kk < 2; ++kk) {
                frag_ab vf = *(const frag_ab*)(vbase + (size_t)(ni * 16 + lo) * NS + t0 + kk * 32 + g * 8);
                acco[ni] = __builtin_amdgcn_mfma_f32_16x16x32_bf16(pf[kk], vf, acco[ni], 0, 0, 0);
            }
    }
    // block-free wave reduction of sumsq, one atomic per wave
#pragma unroll
    for (int off = 32; off; off >>= 1) sumsq += __shfl_xor(sumsq, off, 64);
    if (lane == 0) atomicAdd(&fro[bh], sumsq);
    // write unnormalized O (bf16) at [b, s, h*64+d]
#pragma unroll
    for (int ni = 0; ni < 4; ++ni)
#pragma unroll
        for (int r = 0; r < 4; ++r) {
            int s = srow + g * 4 + r;
            int d = ni * 16 + lo;
            O[((size_t)(b * NS + s)) * ND + h * NHD + d] = f2bf(acco[ni][r]);
        }
}

// ---------------- finalize: inv[i] = 1/(sqrt(fro[i]) + eps) ----------------
__global__ void k_fro(const float* __restrict__ fro, float* __restrict__ inv) {
    int i = threadIdx.x;
    if (i < NB * NH) inv[i] = 1.f / (sqrtf(fro[i]) + 1e-8f);
}

// ---------------- scale O in place by inv_fro[b,h] ----------------
__global__ void __launch_bounds__(256) k_scale(short* __restrict__ O,
                                               const float* __restrict__ inv) {
    int i = blockIdx.x * 256 + threadIdx.x;  // 8 bf16 per thread
    int i8 = i * 8;
    int col = i8 & 511;
    int row = i8 >> 9;
    float sc = inv[(row >> 11) * NH + (col >> 6)];
    frag_ab v = ((frag_ab*)O)[i];
    frag_ab o;
#pragma unroll
    for (int j = 0; j < 8; ++j) o[j] = f2bf(bf2f(v[j]) * sc);
    ((frag_ab*)O)[i] = o;
}

extern "C" void kernel_launch(void* const* d_in, const int* in_sizes, int n_in,
                              void* d_out, int out_size, void* d_ws, size_t ws_size,
                              hipStream_t stream) {
    const float* x     = (const float*)d_in[0];
    const float* Wq    = (const float*)d_in[1];
    const float* bq    = (const float*)d_in[2];
    const float* Wk    = (const float*)d_in[3];
    const float* bk    = (const float*)d_in[4];
    const float* Wv    = (const float*)d_in[5];
    const float* bv    = (const float*)d_in[6];
    const float* mask1 = (const float*)d_in[7];
    const float* mask2 = (const float*)d_in[8];
    const float* Wo    = (const float*)d_in[9];
    const float* bo    = (const float*)d_in[10];
    const int*   roll  = (const int*)d_in[11];
    float* out = (float*)d_out;

    char* ws = (char*)d_ws;
    // workspace layout (bytes)
    short* xb  = (short*)(ws + 0);            // 8192*512*2   = 8388608
    short* Wqb = (short*)(ws + 8388608);      // 512*512*2    = 524288
    short* Wkb = (short*)(ws + 8912896);
    short* Wvb = (short*)(ws + 9437184);
    short* Wob = (short*)(ws + 9961472);
    short* Qb  = (short*)(ws + 10485760);     // 8388608
    short* Kb  = (short*)(ws + 18874368);     // 8388608
    short* Vtb = (short*)(ws + 27262976);     // 8388608
    short* m1t = (short*)(ws + 35651584);     // 524288
    short* m2t = (short*)(ws + 36175872);     // 524288
    short* lm  = (short*)(ws + 36700160);     // 33554432
    short* lmr = (short*)(ws + 70254592);     // 33554432
    short* Ob  = (short*)(ws + 103809024);    // 8388608
    float* fro = (float*)(ws + 112197632);    // 128
    float* inv = (float*)(ws + 112197760);    // 128

    // casts
    k_cast<<<2048, 256, 0, stream>>>(x, xb, (NB * NS * ND) / 8);
    k_cast<<<128, 256, 0, stream>>>(Wq, Wqb, (ND * ND) / 8);
    k_cast<<<128, 256, 0, stream>>>(Wk, Wkb, (ND * ND) / 8);
    k_cast<<<128, 256, 0, stream>>>(Wv, Wvb, (ND * ND) / 8);
    k_cast<<<128, 256, 0, stream>>>(Wo, Wob, (ND * ND) / 8);
    k_tcast_mask<<<dim3(32, 4), 256, 0, stream>>>(mask1, m1t);
    k_tcast_mask<<<dim3(32, 4), 256, 0, stream>>>(mask2, m2t);

    // learnable mask + roll gather
    k_lm<<<dim3(32, 32, 4), 64, 0, stream>>>(m1t, m2t, lm);
    k_roll<<<8192, 256, 0, stream>>>(lm, roll, lmr);

    // projections
    k_gemm<0><<<dim3(8, 64), 256, 0, stream>>>(xb, Wqb, bq, Qb);
    k_gemm<0><<<dim3(8, 64), 256, 0, stream>>>(xb, Wkb, bk, Kb);
    k_gemm<1><<<dim3(8, 64), 256, 0, stream>>>(xb, Wvb, bv, Vtb);

    // attention (needs zeroed fro accumulator)
    hipMemsetAsync(fro, 0, 128, stream);
    k_attn<<<dim3(32, NH, NB), 256, 0, stream>>>(Qb, Kb, Vtb, lmr, Ob, fro);

    // normalize + output projection
    k_fro<<<1, 64, 0, stream>>>(fro, inv);
    k_scale<<<2048, 256, 0, stream>>>(Ob, inv);
    k_gemm<2><<<dim3(8, 64), 256, 0, stream>>>(Ob, Wob, bo, out);
}

// Round 2
// 285.849 us; speedup vs baseline: 1.8888x; 1.8888x over previous
//
#include <hip/hip_runtime.h>
#include <hip/hip_bf16.h>

// Problem constants
#define NB 4
#define NS 2048
#define ND 512
#define NH 8
#define NM 4
#define NR 32
#define NHD 64

typedef short frag_ab __attribute__((ext_vector_type(8)));   // 8 bf16 (bits)
typedef float frag_cd __attribute__((ext_vector_type(4)));   // 4 f32

__device__ __forceinline__ float bf2f(short s) {
    union { unsigned u; float f; } c;
    c.u = ((unsigned)(unsigned short)s) << 16;
    return c.f;
}
__device__ __forceinline__ short f2bf(float f) {
    __hip_bfloat16 h = __float2bfloat16(f);
    union { __hip_bfloat16 h; short s; } c;
    c.h = h;
    return c.s;
}

// async global->LDS, 16B per lane. LDS dest must be base+lane*16 contiguous per wave.
__device__ __forceinline__ void gload16(const void* g, void* l) {
    __builtin_amdgcn_global_load_lds((const __attribute__((address_space(1))) unsigned int*)g,
                                     (__attribute__((address_space(3))) unsigned int*)l,
                                     16, 0, 0);
}

// Stage one 16B chunk of a [nrow][64] bf16 tile (128B rows, 8 chunks/row) with
// XOR swizzle cc ^= (row&7). LDS layout linear; source pre-swizzled (rule #21).
// slot = which 16B chunk this thread handles (0 .. nrow*8-1).
__device__ __forceinline__ void stage_tile(const short* src, size_t srcStride,
                                           char* lbase, int slot) {
    int o = slot * 16;
    int row = o >> 7;
    int cc = ((o >> 4) & 7) ^ (row & 7);
    gload16(src + (size_t)row * srcStride + cc * 8, lbase + o);
}

// Read a bf16x8 fragment from a swizzled [*][64] tile. cc_un = kk*4+g (unswizzled chunk).
__device__ __forceinline__ frag_ab lds_frag(const char* lbase, int row, int cc_un) {
    int cc = cc_un ^ (row & 7);
    return *(const frag_ab*)(lbase + row * 128 + cc * 16);
}

// ---------------- cast f32 -> bf16, 8 elems/thread ----------------
__global__ void __launch_bounds__(256) k_cast(const float* __restrict__ in,
                                              short* __restrict__ out, int n8) {
    int i = blockIdx.x * 256 + threadIdx.x;
    if (i >= n8) return;
    const float4* p = (const float4*)in + (size_t)i * 2;
    float4 a = p[0], b = p[1];
    frag_ab o;
    o[0] = f2bf(a.x); o[1] = f2bf(a.y); o[2] = f2bf(a.z); o[3] = f2bf(a.w);
    o[4] = f2bf(b.x); o[5] = f2bf(b.y); o[6] = f2bf(b.z); o[7] = f2bf(b.w);
    ((frag_ab*)out)[i] = o;
}

// ---------- transpose-cast masks: in[m][r][s] f32 -> out[m][s][r] bf16 ----------
__global__ void __launch_bounds__(256) k_tcast_mask(const float* __restrict__ in,
                                                    short* __restrict__ out) {
    int m = blockIdx.y, s0 = blockIdx.x * 64, tid = threadIdx.x;
    __shared__ float tile[32][65];
    int c = tid & 63, r4 = tid >> 6;
#pragma unroll
    for (int p = 0; p < 8; ++p) {
        int r = p * 4 + r4;
        tile[r][c] = in[(m * 32 + r) * NS + s0 + c];
    }
    __syncthreads();
    int r = tid & 31, s4 = tid >> 5;
#pragma unroll
    for (int p = 0; p < 8; ++p) {
        int s = p * 8 + s4;
        out[(m * NS + s0 + s) * NR + r] = f2bf(tile[r][s]);
    }
}

// ---------------- lm[m][s][t] = sum_r m1t[m][s][r]*m2t[m][t][r] ----------------
__global__ void __launch_bounds__(64) k_lm(const short* __restrict__ m1t,
                                           const short* __restrict__ m2t,
                                           short* __restrict__ lm) {
    int tb = blockIdx.x * 64, sb = blockIdx.y * 64, m = blockIdx.z;
    int lane = threadIdx.x;
    int lo = lane & 15, g = lane >> 4;
    frag_ab a[4], b[4];
#pragma unroll
    for (int i = 0; i < 4; ++i) {
        a[i] = *(const frag_ab*)(m1t + (m * NS + sb + i * 16 + lo) * NR + g * 8);
        b[i] = *(const frag_ab*)(m2t + (m * NS + tb + i * 16 + lo) * NR + g * 8);
    }
#pragma unroll
    for (int mi = 0; mi < 4; ++mi)
#pragma unroll
        for (int ni = 0; ni < 4; ++ni) {
            frag_cd z = {0.f, 0.f, 0.f, 0.f};
            frag_cd d = __builtin_amdgcn_mfma_f32_16x16x32_bf16(a[mi], b[ni], z, 0, 0, 0);
#pragma unroll
            for (int r = 0; r < 4; ++r) {
                int srow = sb + mi * 16 + g * 4 + r;
                int tcol = tb + ni * 16 + lo;
                lm[(size_t)(m * NS + srow) * NS + tcol] = f2bf(d[r]);
            }
        }
}

// ---------------- lmr[m][s][t] = lm[m][s][roll[s][t]] ----------------
__global__ void __launch_bounds__(256) k_roll(const short* __restrict__ lm,
                                              const int* __restrict__ roll,
                                              short* __restrict__ lmr) {
    int bid = blockIdx.x;
    int m = bid & 3, s = bid >> 2;
    __shared__ __align__(16) short row[NS];
    int tid = threadIdx.x;
    size_t base = (size_t)(m * NS + s) * NS;
    *(frag_ab*)(row + tid * 8) = *(const frag_ab*)(lm + base + tid * 8);
    __syncthreads();
    const int* rrow = roll + (size_t)s * NS;
#pragma unroll
    for (int k = 0; k < 8; ++k) {
        int t = k * 256 + tid;
        lmr[base + t] = row[rrow[t]];
    }
}

// ---------------- LDS-staged bf16 MFMA GEMM: C[8192x512] = A * W^T + bias --------
// 128x128 tile, BK=64, 2-phase double-buffered global_load_lds staging.
// MODE 0: out bf16 [b,h,s,d]; MODE 1: out bf16 [b,h,d,s] (V^T); MODE 2: out f32 flat.
template <int MODE>
__global__ void __launch_bounds__(256) k_gemm(const short* __restrict__ A,
                                              const short* __restrict__ W,
                                              const float* __restrict__ bias,
                                              void* __restrict__ out) {
    int n = blockIdx.x;
    int Mb = (n & 7) * 8 + ((n >> 3) & 7);   // XCD n&7 owns contiguous A-panel
    int Nb = n >> 6;
    int bm0 = Mb * 128, bn0 = Nb * 128;
    int tid = threadIdx.x;
    int wid = tid >> 6, lane = tid & 63;
    int lo = lane & 15, g = lane >> 4;
    int wr = (wid >> 1) * 64, wc = (wid & 1) * 64;

    __shared__ __align__(16) char sm[2][32768];   // A tile 16KB @0, B tile 16KB @16384

    frag_cd acc[4][4];
#pragma unroll
    for (int mi = 0; mi < 4; ++mi)
#pragma unroll
        for (int ni = 0; ni < 4; ++ni) acc[mi][ni] = (frag_cd){0.f, 0.f, 0.f, 0.f};

    const short* Abase = A + (size_t)bm0 * ND;
    const short* Wbase = W + (size_t)bn0 * ND;

    // prologue: stage k0=0 into buffer 0
#pragma unroll
    for (int j = 0; j < 4; ++j) stage_tile(Abase, ND, sm[0], tid + j * 256);
#pragma unroll
    for (int j = 0; j < 4; ++j) stage_tile(Wbase, ND, sm[0] + 16384, tid + j * 256);
    __syncthreads();

    char* cb = sm[0];
    char* nb = sm[1];
    for (int kt = 0; kt < 8; ++kt) {
        if (kt < 7) {
            int k0 = (kt + 1) * 64;
#pragma unroll
            for (int j = 0; j < 4; ++j) stage_tile(Abase + k0, ND, nb, tid + j * 256);
#pragma unroll
            for (int j = 0; j < 4; ++j) stage_tile(Wbase + k0, ND, nb + 16384, tid + j * 256);
        }
#pragma unroll
        for (int kk = 0; kk < 2; ++kk) {
            frag_ab af[4], bf[4];
#pragma unroll
            for (int mi = 0; mi < 4; ++mi) af[mi] = lds_frag(cb, wr + mi * 16 + lo, kk * 4 + g);
#pragma unroll
            for (int ni = 0; ni < 4; ++ni) bf[ni] = lds_frag(cb + 16384, wc + ni * 16 + lo, kk * 4 + g);
#pragma unroll
            for (int mi = 0; mi < 4; ++mi)
#pragma unroll
                for (int ni = 0; ni < 4; ++ni)
                    acc[mi][ni] = __builtin_amdgcn_mfma_f32_16x16x32_bf16(af[mi], bf[ni], acc[mi][ni], 0, 0, 0);
        }
        __syncthreads();
        char* t = cb; cb = nb; nb = t;
    }

#pragma unroll
    for (int mi = 0; mi < 4; ++mi)
#pragma unroll
        for (int ni = 0; ni < 4; ++ni)
#pragma unroll
            for (int r = 0; r < 4; ++r) {
                int row = bm0 + wr + mi * 16 + g * 4 + r;
                int col = bn0 + wc + ni * 16 + lo;
                float v = acc[mi][ni][r] + bias[col];
                int b = row >> 11, s = row & 2047, h = col >> 6, d = col & 63;
                if (MODE == 0) {
                    ((short*)out)[(((size_t)(b * NH + h) * NS + s) << 6) + d] = f2bf(v);
                } else if (MODE == 1) {
                    ((short*)out)[((size_t)(b * NH + h) * NHD + d) * NS + s] = f2bf(v);
                } else {
                    ((float*)out)[(size_t)row * ND + col] = v;
                }
            }
}

// ---------------- fused attention: O_unnorm = (QK^T/8 * lm_rolled) @ V ; sumsq ----
// 8 waves x 16 s-rows = 128 rows/block; K/V t-tiles (64) double-buffered in LDS.
__global__ void __launch_bounds__(512) k_attn(const short* __restrict__ Qb,
                                              const short* __restrict__ Kb,
                                              const short* __restrict__ Vt,
                                              const short* __restrict__ lmr,
                                              short* __restrict__ O,
                                              float* __restrict__ fro) {
    int n = blockIdx.x;              // 0..511, XCD-swizzled: xcd = n&7 -> same h
    int h = n & 7;
    int slot = n >> 3;
    int b = slot >> 4;
    int sb = slot & 15;
    int bh = b * NH + h;
    int m = h & 3;
    int tid = threadIdx.x;
    int w = tid >> 6, lane = tid & 63;
    int lo = lane & 15, g = lane >> 4;
    int srow = sb * 128 + w * 16;    // wave's 16-row s-base

    __shared__ __align__(16) char kv[2][16384];   // K tile 8KB @0, V^T tile 8KB @8192
    __shared__ __align__(16) short plds[8][1024]; // 2KB per wave, wave-private
    char* pbase = (char*)&plds[w][0];

    const short* kbase = Kb + (size_t)bh * NS * NHD;
    const short* vbase = Vt + (size_t)bh * NHD * NS;
    const short* lmbase = lmr + ((size_t)m * NS + srow + lo) * NS;

    const short* qptr = Qb + ((size_t)bh * NS + srow + lo) * NHD + g * 8;
    frag_ab qf[2];
    qf[0] = *(const frag_ab*)(qptr);
    qf[1] = *(const frag_ab*)(qptr + 32);

    frag_cd acco[4];
#pragma unroll
    for (int ni = 0; ni < 4; ++ni) acco[ni] = (frag_cd){0.f, 0.f, 0.f, 0.f};
    float sumsq = 0.f;

    // prologue: stage t-block 0
    stage_tile(kbase, NHD, kv[0], tid);            // K rows = t (64), stride 64
    stage_tile(vbase, NS, kv[0] + 8192, tid);      // V^T rows = d (64), stride 2048
    __syncthreads();

    char* cb = kv[0];
    char* nb = kv[1];
    for (int tb = 0; tb < 32; ++tb) {
        int t0 = tb * 64;
        if (tb < 31) {
            stage_tile(kbase + (size_t)(t0 + 64) * NHD, NHD, nb, tid);
            stage_tile(vbase + (t0 + 64), NS, nb + 8192, tid);
        }
        // QK^T
        frag_cd sacc[4];
#pragma unroll
        for (int ni = 0; ni < 4; ++ni) sacc[ni] = (frag_cd){0.f, 0.f, 0.f, 0.f};
#pragma unroll
        for (int kk = 0; kk < 2; ++kk)
#pragma unroll
            for (int ni = 0; ni < 4; ++ni)
                sacc[ni] = __builtin_amdgcn_mfma_f32_16x16x32_bf16(
                    qf[kk], lds_frag(cb, ni * 16 + lo, kk * 4 + g), sacc[ni], 0, 0, 0);
        // scores (D-layout) -> wave-private LDS, XOR-swizzled rows
#pragma unroll
        for (int ni = 0; ni < 4; ++ni)
#pragma unroll
            for (int r = 0; r < 4; ++r) {
                int rs = g * 4 + r;
                int ct = ni * 16 + lo;
                int byte = (rs * 128 + ct * 2) ^ ((rs & 7) << 4);
                *(short*)(pbase + byte) = f2bf(sacc[ni][r]);
            }
        // read back in A-layout, multiply lm/8, accumulate sumsq, pack bf16
        frag_ab pf[2];
#pragma unroll
        for (int kk = 0; kk < 2; ++kk) {
            int rbyte = (lo * 128 + kk * 64 + g * 16) ^ ((lo & 7) << 4);
            frag_ab sf = *(const frag_ab*)(pbase + rbyte);
            frag_ab lf = *(const frag_ab*)(lmbase + t0 + kk * 32 + g * 8);
            frag_ab pp;
#pragma unroll
            for (int j = 0; j < 8; ++j) {
                float p = bf2f(sf[j]) * bf2f(lf[j]) * 0.125f;
                sumsq += p * p;
                pp[j] = f2bf(p);
            }
            pf[kk] = pp;
        }
        // PV
#pragma unroll
        for (int ni = 0; ni < 4; ++ni)
#pragma unroll
            for (int kk = 0; kk < 2; ++kk)
                acco[ni] = __builtin_amdgcn_mfma_f32_16x16x32_bf16(
                    pf[kk], lds_frag(cb + 8192, ni * 16 + lo, kk * 4 + g), acco[ni], 0, 0, 0);
        __syncthreads();
        char* t = cb; cb = nb; nb = t;
    }
    // wave reduction of sumsq, one atomic per wave
#pragma unroll
    for (int off = 32; off; off >>= 1) sumsq += __shfl_xor(sumsq, off, 64);
    if (lane == 0) atomicAdd(&fro[bh], sumsq);
    // write unnormalized O (bf16) at [b, s, h*64+d]
#pragma unroll
    for (int ni = 0; ni < 4; ++ni)
#pragma unroll
        for (int r = 0; r < 4; ++r) {
            int s = srow + g * 4 + r;
            int d = ni * 16 + lo;
            O[((size_t)(b * NS + s)) * ND + h * NHD + d] = f2bf(acco[ni][r]);
        }
}

// ---------------- finalize: inv[i] = 1/(sqrt(fro[i]) + eps) ----------------
__global__ void k_fro(const float* __restrict__ fro, float* __restrict__ inv) {
    int i = threadIdx.x;
    if (i < NB * NH) inv[i] = 1.f / (sqrtf(fro[i]) + 1e-8f);
}

// ---------------- scale O in place by inv_fro[b,h] ----------------
__global__ void __launch_bounds__(256) k_scale(short* __restrict__ O,
                                               const float* __restrict__ inv) {
    int i = blockIdx.x * 256 + threadIdx.x;  // 8 bf16 per thread
    int i8 = i * 8;
    int col = i8 & 511;
    int row = i8 >> 9;
    float sc = inv[(row >> 11) * NH + (col >> 6)];
    frag_ab v = ((frag_ab*)O)[i];
    frag_ab o;
#pragma unroll
    for (int j = 0; j < 8; ++j) o[j] = f2bf(bf2f(v[j]) * sc);
    ((frag_ab*)O)[i] = o;
}

extern "C" void kernel_launch(void* const* d_in, const int* in_sizes, int n_in,
                              void* d_out, int out_size, void* d_ws, size_t ws_size,
                              hipStream_t stream) {
    const float* x     = (const float*)d_in[0];
    const float* Wq    = (const float*)d_in[1];
    const float* bq    = (const float*)d_in[2];
    const float* Wk    = (const float*)d_in[3];
    const float* bk    = (const float*)d_in[4];
    const float* Wv    = (const float*)d_in[5];
    const float* bv    = (const float*)d_in[6];
    const float* mask1 = (const float*)d_in[7];
    const float* mask2 = (const float*)d_in[8];
    const float* Wo    = (const float*)d_in[9];
    const float* bo    = (const float*)d_in[10];
    const int*   roll  = (const int*)d_in[11];
    float* out = (float*)d_out;

    char* ws = (char*)d_ws;
    short* xb  = (short*)(ws + 0);            // 8388608
    short* Wqb = (short*)(ws + 8388608);      // 524288
    short* Wkb = (short*)(ws + 8912896);
    short* Wvb = (short*)(ws + 9437184);
    short* Wob = (short*)(ws + 9961472);
    short* Qb  = (short*)(ws + 10485760);     // 8388608
    short* Kb  = (short*)(ws + 18874368);     // 8388608
    short* Vtb = (short*)(ws + 27262976);     // 8388608
    short* m1t = (short*)(ws + 35651584);     // 524288
    short* m2t = (short*)(ws + 36175872);     // 524288
    short* lm  = (short*)(ws + 36700160);     // 33554432
    short* lmr = (short*)(ws + 70254592);     // 33554432
    short* Ob  = (short*)(ws + 103809024);    // 8388608
    float* fro = (float*)(ws + 112197632);    // 128
    float* inv = (float*)(ws + 112197760);    // 128

    // casts
    k_cast<<<2048, 256, 0, stream>>>(x, xb, (NB * NS * ND) / 8);
    k_cast<<<128, 256, 0, stream>>>(Wq, Wqb, (ND * ND) / 8);
    k_cast<<<128, 256, 0, stream>>>(Wk, Wkb, (ND * ND) / 8);
    k_cast<<<128, 256, 0, stream>>>(Wv, Wvb, (ND * ND) / 8);
    k_cast<<<128, 256, 0, stream>>>(Wo, Wob, (ND * ND) / 8);
    k_tcast_mask<<<dim3(32, 4), 256, 0, stream>>>(mask1, m1t);
    k_tcast_mask<<<dim3(32, 4), 256, 0, stream>>>(mask2, m2t);

    // learnable mask + roll gather
    k_lm<<<dim3(32, 32, 4), 64, 0, stream>>>(m1t, m2t, lm);
    k_roll<<<8192, 256, 0, stream>>>(lm, roll, lmr);

    // projections (LDS-staged GEMMs, 256 blocks each)
    k_gemm<0><<<256, 256, 0, stream>>>(xb, Wqb, bq, Qb);
    k_gemm<0><<<256, 256, 0, stream>>>(xb, Wkb, bk, Kb);
    k_gemm<1><<<256, 256, 0, stream>>>(xb, Wvb, bv, Vtb);

    // attention (needs zeroed fro accumulator)
    hipMemsetAsync(fro, 0, 128, stream);
    k_attn<<<512, 512, 0, stream>>>(Qb, Kb, Vtb, lmr, Ob, fro);

    // normalize + output projection
    k_fro<<<1, 64, 0, stream>>>(fro, inv);
    k_scale<<<2048, 256, 0, stream>>>(Ob, inv);
    k_gemm<2><<<256, 256, 0, stream>>>(Ob, Wob, bo, out);
}

// Round 3
// 252.912 us; speedup vs baseline: 2.1348x; 1.1302x over previous
//
#include <hip/hip_runtime.h>
#include <hip/hip_bf16.h>

// Problem constants
#define NB 4
#define NS 2048
#define ND 512
#define NH 8
#define NM 4
#define NR 32
#define NHD 64

typedef short frag_ab __attribute__((ext_vector_type(8)));   // 8 bf16 (bits)
typedef float frag_cd __attribute__((ext_vector_type(4)));   // 4 f32

__device__ __forceinline__ float bf2f(short s) {
    union { unsigned u; float f; } c;
    c.u = ((unsigned)(unsigned short)s) << 16;
    return c.f;
}
__device__ __forceinline__ short f2bf(float f) {
    __hip_bfloat16 h = __float2bfloat16(f);
    union { __hip_bfloat16 h; short s; } c;
    c.h = h;
    return c.s;
}

// async global->LDS, 16B per lane. LDS dest must be base+lane*16 contiguous per wave.
__device__ __forceinline__ void gload16(const void* g, void* l) {
    __builtin_amdgcn_global_load_lds((const __attribute__((address_space(1))) unsigned int*)g,
                                     (__attribute__((address_space(3))) unsigned int*)l,
                                     16, 0, 0);
}

// Stage one 16B chunk of a [nrow][64] bf16 tile (128B rows, 8 chunks/row) with
// XOR swizzle cc ^= (row&7). LDS layout linear; source pre-swizzled (rule #21).
__device__ __forceinline__ void stage_tile(const short* src, size_t srcStride,
                                           char* lbase, int slot) {
    int o = slot * 16;
    int row = o >> 7;
    int cc = ((o >> 4) & 7) ^ (row & 7);
    gload16(src + (size_t)row * srcStride + cc * 8, lbase + o);
}

// Read a bf16x8 fragment from a swizzled [*][64] tile. cc_un = kk*4+g (unswizzled chunk).
__device__ __forceinline__ frag_ab lds_frag(const char* lbase, int row, int cc_un) {
    int cc = cc_un ^ (row & 7);
    return *(const frag_ab*)(lbase + row * 128 + cc * 16);
}

// ---------------- cast f32 -> bf16, 8 elems/thread ----------------
__global__ void __launch_bounds__(256) k_cast(const float* __restrict__ in,
                                              short* __restrict__ out, int n8) {
    int i = blockIdx.x * 256 + threadIdx.x;
    if (i >= n8) return;
    const float4* p = (const float4*)in + (size_t)i * 2;
    float4 a = p[0], b = p[1];
    frag_ab o;
    o[0] = f2bf(a.x); o[1] = f2bf(a.y); o[2] = f2bf(a.z); o[3] = f2bf(a.w);
    o[4] = f2bf(b.x); o[5] = f2bf(b.y); o[6] = f2bf(b.z); o[7] = f2bf(b.w);
    ((frag_ab*)out)[i] = o;
}

// ---------------- merged weight cast: Wq|Wk|Wv|Wo -> contiguous bf16 ----------------
__global__ void __launch_bounds__(256) k_castw(const float* __restrict__ Wq,
                                               const float* __restrict__ Wk,
                                               const float* __restrict__ Wv,
                                               const float* __restrict__ Wo,
                                               short* __restrict__ out) {
    int i = blockIdx.x * 256 + threadIdx.x;   // 0..131071 frags
    int which = i >> 15;                      // 32768 frags per weight
    int j = i & 32767;
    const float* src = which == 0 ? Wq : which == 1 ? Wk : which == 2 ? Wv : Wo;
    const float4* p = (const float4*)src + (size_t)j * 2;
    float4 a = p[0], b = p[1];
    frag_ab o;
    o[0] = f2bf(a.x); o[1] = f2bf(a.y); o[2] = f2bf(a.z); o[3] = f2bf(a.w);
    o[4] = f2bf(b.x); o[5] = f2bf(b.y); o[6] = f2bf(b.z); o[7] = f2bf(b.w);
    ((frag_ab*)out)[i] = o;
}

// ---------- transpose-cast masks: in[m][r][s] f32 -> out[m][s][r] bf16 (both masks) ----------
__global__ void __launch_bounds__(256) k_tcast_mask(const float* __restrict__ mask1,
                                                    const float* __restrict__ mask2,
                                                    short* __restrict__ m1t,
                                                    short* __restrict__ m2t) {
    int my = blockIdx.y;
    const float* in = my < 4 ? mask1 : mask2;
    short* out = my < 4 ? m1t : m2t;
    int m = my & 3;
    int s0 = blockIdx.x * 64, tid = threadIdx.x;
    __shared__ float tile[32][65];
    int c = tid & 63, r4 = tid >> 6;
#pragma unroll
    for (int p = 0; p < 8; ++p) {
        int r = p * 4 + r4;
        tile[r][c] = in[(m * 32 + r) * NS + s0 + c];
    }
    __syncthreads();
    int r = tid & 31, s4 = tid >> 5;
#pragma unroll
    for (int p = 0; p < 8; ++p) {
        int s = p * 8 + s4;
        out[(m * NS + s0 + s) * NR + r] = f2bf(tile[r][s]);
    }
}

// ---------------- lm[m][s][t] = sum_r m1t[m][s][r]*m2t[m][t][r] ----------------
__global__ void __launch_bounds__(64) k_lm(const short* __restrict__ m1t,
                                           const short* __restrict__ m2t,
                                           short* __restrict__ lm) {
    int tb = blockIdx.x * 64, sb = blockIdx.y * 64, m = blockIdx.z;
    int lane = threadIdx.x;
    int lo = lane & 15, g = lane >> 4;
    frag_ab a[4], b[4];
#pragma unroll
    for (int i = 0; i < 4; ++i) {
        a[i] = *(const frag_ab*)(m1t + (m * NS + sb + i * 16 + lo) * NR + g * 8);
        b[i] = *(const frag_ab*)(m2t + (m * NS + tb + i * 16 + lo) * NR + g * 8);
    }
#pragma unroll
    for (int mi = 0; mi < 4; ++mi)
#pragma unroll
        for (int ni = 0; ni < 4; ++ni) {
            frag_cd z = {0.f, 0.f, 0.f, 0.f};
            frag_cd d = __builtin_amdgcn_mfma_f32_16x16x32_bf16(a[mi], b[ni], z, 0, 0, 0);
#pragma unroll
            for (int r = 0; r < 4; ++r) {
                int srow = sb + mi * 16 + g * 4 + r;
                int tcol = tb + ni * 16 + lo;
                lm[(size_t)(m * NS + srow) * NS + tcol] = f2bf(d[r]);
            }
        }
}

// ---------------- lmr[m][s][t] = lm[m][s][roll[s][t]] ----------------
__global__ void __launch_bounds__(256) k_roll(const short* __restrict__ lm,
                                              const int* __restrict__ roll,
                                              short* __restrict__ lmr) {
    int bid = blockIdx.x;
    int m = bid & 3, s = bid >> 2;
    __shared__ __align__(16) short row[NS];
    int tid = threadIdx.x;
    size_t base = (size_t)(m * NS + s) * NS;
    *(frag_ab*)(row + tid * 8) = *(const frag_ab*)(lm + base + tid * 8);
    __syncthreads();
    const int* rrow = roll + (size_t)s * NS;
    int t0 = tid * 8;
    int4 r0 = *(const int4*)(rrow + t0);
    int4 r1 = *(const int4*)(rrow + t0 + 4);
    frag_ab o;
    o[0] = row[r0.x]; o[1] = row[r0.y]; o[2] = row[r0.z]; o[3] = row[r0.w];
    o[4] = row[r1.x]; o[5] = row[r1.y]; o[6] = row[r1.z]; o[7] = row[r1.w];
    *(frag_ab*)(lmr + base + t0) = o;
}

// ---------------- fused QKV GEMM: 128x64 tile, BK=64, double-buffered LDS ----------
// Nb 0..23: which = Nb>>3 (0=Q,1=K,2=V), bn0 = (Nb&7)*64.
__global__ void __launch_bounds__(256) k_gemm_qkv(const short* __restrict__ A,
                                                  const short* __restrict__ Wqb,
                                                  const short* __restrict__ Wkb,
                                                  const short* __restrict__ Wvb,
                                                  const float* __restrict__ bq,
                                                  const float* __restrict__ bk,
                                                  const float* __restrict__ bv,
                                                  short* __restrict__ Qb,
                                                  short* __restrict__ Kb,
                                                  short* __restrict__ Vtb) {
    int n = blockIdx.x;                 // 1536
    int rr = n >> 3;
    int Mb = (n & 7) * 8 + (rr & 7);    // XCD-contiguous A panels
    int Nb = rr >> 3;                   // 0..23
    int which = Nb >> 3;
    int bn0 = (Nb & 7) * 64;
    const short* W = which == 0 ? Wqb : which == 1 ? Wkb : Wvb;
    const float* bias = which == 0 ? bq : which == 1 ? bk : bv;
    short* out = which == 0 ? Qb : which == 1 ? Kb : Vtb;
    int bm0 = Mb * 128;
    int tid = threadIdx.x;
    int wid = tid >> 6, lane = tid & 63;
    int lo = lane & 15, g = lane >> 4;
    int wr = (wid >> 1) * 64, wc = (wid & 1) * 32;

    __shared__ __align__(16) char sm[2][24576];   // A 16KB @0, B 8KB @16384

    frag_cd acc[4][2];
#pragma unroll
    for (int mi = 0; mi < 4; ++mi)
#pragma unroll
        for (int ni = 0; ni < 2; ++ni) acc[mi][ni] = (frag_cd){0.f, 0.f, 0.f, 0.f};

    const short* Abase = A + (size_t)bm0 * ND;
    const short* Wbase = W + (size_t)bn0 * ND;

#pragma unroll
    for (int j = 0; j < 4; ++j) stage_tile(Abase, ND, sm[0], tid + j * 256);
#pragma unroll
    for (int j = 0; j < 2; ++j) stage_tile(Wbase, ND, sm[0] + 16384, tid + j * 256);
    __syncthreads();

    char* cb = sm[0];
    char* nb = sm[1];
    for (int kt = 0; kt < 8; ++kt) {
        if (kt < 7) {
            int k0 = (kt + 1) * 64;
#pragma unroll
            for (int j = 0; j < 4; ++j) stage_tile(Abase + k0, ND, nb, tid + j * 256);
#pragma unroll
            for (int j = 0; j < 2; ++j) stage_tile(Wbase + k0, ND, nb + 16384, tid + j * 256);
        }
#pragma unroll
        for (int kk = 0; kk < 2; ++kk) {
            frag_ab af[4], bf[2];
#pragma unroll
            for (int mi = 0; mi < 4; ++mi) af[mi] = lds_frag(cb, wr + mi * 16 + lo, kk * 4 + g);
#pragma unroll
            for (int ni = 0; ni < 2; ++ni) bf[ni] = lds_frag(cb + 16384, wc + ni * 16 + lo, kk * 4 + g);
#pragma unroll
            for (int mi = 0; mi < 4; ++mi)
#pragma unroll
                for (int ni = 0; ni < 2; ++ni)
                    acc[mi][ni] = __builtin_amdgcn_mfma_f32_16x16x32_bf16(af[mi], bf[ni], acc[mi][ni], 0, 0, 0);
        }
        __syncthreads();
        char* t = cb; cb = nb; nb = t;
    }

#pragma unroll
    for (int mi = 0; mi < 4; ++mi)
#pragma unroll
        for (int ni = 0; ni < 2; ++ni)
#pragma unroll
            for (int ri = 0; ri < 4; ++ri) {
                int row = bm0 + wr + mi * 16 + g * 4 + ri;
                int col = bn0 + wc + ni * 16 + lo;
                float v = acc[mi][ni][ri] + bias[col];
                int b = row >> 11, s = row & 2047, h = col >> 6, d = col & 63;
                if (which < 2) {
                    out[(((size_t)(b * NH + h) * NS + s) << 6) + d] = f2bf(v);
                } else {
                    out[((size_t)(b * NH + h) * NHD + d) * NS + s] = f2bf(v);
                }
            }
}

// ---------------- output GEMM: C f32 = A(bf16) * W^T + bias, 128x64 tile ----------------
__global__ void __launch_bounds__(256) k_gemm_out(const short* __restrict__ A,
                                                  const short* __restrict__ W,
                                                  const float* __restrict__ bias,
                                                  float* __restrict__ out) {
    int n = blockIdx.x;                 // 512
    int rr = n >> 3;
    int Mb = (n & 7) * 8 + (rr & 7);
    int Nb = rr >> 3;                   // 0..7
    int bn0 = Nb * 64;
    int bm0 = Mb * 128;
    int tid = threadIdx.x;
    int wid = tid >> 6, lane = tid & 63;
    int lo = lane & 15, g = lane >> 4;
    int wr = (wid >> 1) * 64, wc = (wid & 1) * 32;

    __shared__ __align__(16) char sm[2][24576];

    frag_cd acc[4][2];
#pragma unroll
    for (int mi = 0; mi < 4; ++mi)
#pragma unroll
        for (int ni = 0; ni < 2; ++ni) acc[mi][ni] = (frag_cd){0.f, 0.f, 0.f, 0.f};

    const short* Abase = A + (size_t)bm0 * ND;
    const short* Wbase = W + (size_t)bn0 * ND;

#pragma unroll
    for (int j = 0; j < 4; ++j) stage_tile(Abase, ND, sm[0], tid + j * 256);
#pragma unroll
    for (int j = 0; j < 2; ++j) stage_tile(Wbase, ND, sm[0] + 16384, tid + j * 256);
    __syncthreads();

    char* cb = sm[0];
    char* nb = sm[1];
    for (int kt = 0; kt < 8; ++kt) {
        if (kt < 7) {
            int k0 = (kt + 1) * 64;
#pragma unroll
            for (int j = 0; j < 4; ++j) stage_tile(Abase + k0, ND, nb, tid + j * 256);
#pragma unroll
            for (int j = 0; j < 2; ++j) stage_tile(Wbase + k0, ND, nb + 16384, tid + j * 256);
        }
#pragma unroll
        for (int kk = 0; kk < 2; ++kk) {
            frag_ab af[4], bf[2];
#pragma unroll
            for (int mi = 0; mi < 4; ++mi) af[mi] = lds_frag(cb, wr + mi * 16 + lo, kk * 4 + g);
#pragma unroll
            for (int ni = 0; ni < 2; ++ni) bf[ni] = lds_frag(cb + 16384, wc + ni * 16 + lo, kk * 4 + g);
#pragma unroll
            for (int mi = 0; mi < 4; ++mi)
#pragma unroll
                for (int ni = 0; ni < 2; ++ni)
                    acc[mi][ni] = __builtin_amdgcn_mfma_f32_16x16x32_bf16(af[mi], bf[ni], acc[mi][ni], 0, 0, 0);
        }
        __syncthreads();
        char* t = cb; cb = nb; nb = t;
    }

#pragma unroll
    for (int mi = 0; mi < 4; ++mi)
#pragma unroll
        for (int ni = 0; ni < 2; ++ni)
#pragma unroll
            for (int ri = 0; ri < 4; ++ri) {
                int row = bm0 + wr + mi * 16 + g * 4 + ri;
                int col = bn0 + wc + ni * 16 + lo;
                out[(size_t)row * ND + col] = acc[mi][ni][ri] + bias[col];
            }
}

// ---------------- fused attention: O_unnorm = (QK^T/8 * lm_rolled) @ V ; sumsq ----
// 8 waves x 16 s-rows = 128 rows/block; K/V t-tiles (64) double-buffered in LDS.
// Grid 512, XCD key = (m, sb-half) so lm t-slices are L2-resident with 8-block reuse.
__global__ void __launch_bounds__(512) k_attn(const short* __restrict__ Qb,
                                              const short* __restrict__ Kb,
                                              const short* __restrict__ Vt,
                                              const short* __restrict__ lmr,
                                              short* __restrict__ O,
                                              float* __restrict__ fro) {
    int n = blockIdx.x;              // 0..511
    int xcd = n & 7;
    int idx = n >> 3;                // 0..63
    int b = idx & 3;
    int hh = (idx >> 2) & 1;
    int sbl = idx >> 3;              // 0..7
    int m = xcd >> 1;
    int sb = (xcd & 1) * 8 + sbl;    // 0..15
    int h = hh * 4 + m;
    int bh = b * NH + h;
    int tid = threadIdx.x;
    int w = tid >> 6, lane = tid & 63;
    int lo = lane & 15, g = lane >> 4;
    int srow = sb * 128 + w * 16;    // wave's 16-row s-base

    __shared__ __align__(16) char kv[2][16384];   // K tile 8KB @0, V^T tile 8KB @8192
    __shared__ __align__(16) short plds[8][1024]; // 2KB per wave, wave-private
    char* pbase = (char*)&plds[w][0];

    const short* kbase = Kb + (size_t)bh * NS * NHD;
    const short* vbase = Vt + (size_t)bh * NHD * NS;
    const short* lmbase = lmr + ((size_t)m * NS + srow + lo) * NS;

    const short* qptr = Qb + ((size_t)bh * NS + srow + lo) * NHD + g * 8;
    frag_ab qf[2];
    qf[0] = *(const frag_ab*)(qptr);
    qf[1] = *(const frag_ab*)(qptr + 32);

    frag_cd acco[4];
#pragma unroll
    for (int ni = 0; ni < 4; ++ni) acco[ni] = (frag_cd){0.f, 0.f, 0.f, 0.f};
    float sumsq = 0.f;

    // prologue: stage t-block 0; prefetch lm frags for t-block 0
    stage_tile(kbase, NHD, kv[0], tid);
    stage_tile(vbase, NS, kv[0] + 8192, tid);
    frag_ab lc0 = *(const frag_ab*)(lmbase + g * 8);
    frag_ab lc1 = *(const frag_ab*)(lmbase + 32 + g * 8);
    __syncthreads();

    char* cb = kv[0];
    char* nb = kv[1];
    for (int tb = 0; tb < 32; ++tb) {
        int t0 = tb * 64;
        frag_ab ln0 = lc0, ln1 = lc1;
        if (tb < 31) {
            // stage next K/V tile; prefetch next lm frags into registers
            stage_tile(kbase + (size_t)(t0 + 64) * NHD, NHD, nb, tid);
            stage_tile(vbase + (t0 + 64), NS, nb + 8192, tid);
            ln0 = *(const frag_ab*)(lmbase + t0 + 64 + g * 8);
            ln1 = *(const frag_ab*)(lmbase + t0 + 96 + g * 8);
        }
        // QK^T
        frag_cd sacc[4];
#pragma unroll
        for (int ni = 0; ni < 4; ++ni) sacc[ni] = (frag_cd){0.f, 0.f, 0.f, 0.f};
#pragma unroll
        for (int kk = 0; kk < 2; ++kk)
#pragma unroll
            for (int ni = 0; ni < 4; ++ni)
                sacc[ni] = __builtin_amdgcn_mfma_f32_16x16x32_bf16(
                    qf[kk], lds_frag(cb, ni * 16 + lo, kk * 4 + g), sacc[ni], 0, 0, 0);
        // scores (D-layout) -> wave-private LDS, XOR-swizzled rows
#pragma unroll
        for (int ni = 0; ni < 4; ++ni)
#pragma unroll
            for (int r = 0; r < 4; ++r) {
                int rs = g * 4 + r;
                int ct = ni * 16 + lo;
                int byte = (rs * 128 + ct * 2) ^ ((rs & 7) << 4);
                *(short*)(pbase + byte) = f2bf(sacc[ni][r]);
            }
        // read back in A-layout, multiply lm/8, accumulate sumsq, pack bf16
        frag_ab pf[2];
#pragma unroll
        for (int kk = 0; kk < 2; ++kk) {
            int rbyte = (lo * 128 + kk * 64 + g * 16) ^ ((lo & 7) << 4);
            frag_ab sf = *(const frag_ab*)(pbase + rbyte);
            frag_ab lf = kk ? lc1 : lc0;
            frag_ab pp;
#pragma unroll
            for (int j = 0; j < 8; ++j) {
                float p = bf2f(sf[j]) * bf2f(lf[j]) * 0.125f;
                sumsq += p * p;
                pp[j] = f2bf(p);
            }
            pf[kk] = pp;
        }
        // PV
#pragma unroll
        for (int ni = 0; ni < 4; ++ni)
#pragma unroll
            for (int kk = 0; kk < 2; ++kk)
                acco[ni] = __builtin_amdgcn_mfma_f32_16x16x32_bf16(
                    pf[kk], lds_frag(cb + 8192, ni * 16 + lo, kk * 4 + g), acco[ni], 0, 0, 0);
        lc0 = ln0;
        lc1 = ln1;
        __syncthreads();
        char* t = cb; cb = nb; nb = t;
    }
    // wave reduction of sumsq, one atomic per wave
#pragma unroll
    for (int off = 32; off; off >>= 1) sumsq += __shfl_xor(sumsq, off, 64);
    if (lane == 0) atomicAdd(&fro[bh], sumsq);
    // write unnormalized O (bf16) at [b, s, h*64+d]
#pragma unroll
    for (int ni = 0; ni < 4; ++ni)
#pragma unroll
        for (int r = 0; r < 4; ++r) {
            int s = srow + g * 4 + r;
            int d = ni * 16 + lo;
            O[((size_t)(b * NS + s)) * ND + h * NHD + d] = f2bf(acco[ni][r]);
        }
}

// ---------------- scale O in place by 1/(sqrt(fro[b,h])+eps) ----------------
__global__ void __launch_bounds__(256) k_scale(short* __restrict__ O,
                                               const float* __restrict__ fro) {
    int i = blockIdx.x * 256 + threadIdx.x;  // 8 bf16 per thread
    int i8 = i * 8;
    int col = i8 & 511;
    int row = i8 >> 9;
    float f = fro[(row >> 11) * NH + (col >> 6)];
    float sc = 1.f / (sqrtf(f) + 1e-8f);
    frag_ab v = ((frag_ab*)O)[i];
    frag_ab o;
#pragma unroll
    for (int j = 0; j < 8; ++j) o[j] = f2bf(bf2f(v[j]) * sc);
    ((frag_ab*)O)[i] = o;
}

extern "C" void kernel_launch(void* const* d_in, const int* in_sizes, int n_in,
                              void* d_out, int out_size, void* d_ws, size_t ws_size,
                              hipStream_t stream) {
    const float* x     = (const float*)d_in[0];
    const float* Wq    = (const float*)d_in[1];
    const float* bq    = (const float*)d_in[2];
    const float* Wk    = (const float*)d_in[3];
    const float* bk    = (const float*)d_in[4];
    const float* Wv    = (const float*)d_in[5];
    const float* bv    = (const float*)d_in[6];
    const float* mask1 = (const float*)d_in[7];
    const float* mask2 = (const float*)d_in[8];
    const float* Wo    = (const float*)d_in[9];
    const float* bo    = (const float*)d_in[10];
    const int*   roll  = (const int*)d_in[11];
    float* out = (float*)d_out;

    char* ws = (char*)d_ws;
    short* xb  = (short*)(ws + 0);            // 8388608
    short* Wqb = (short*)(ws + 8388608);      // 524288 (Wq|Wk|Wv|Wo contiguous)
    short* Wkb = (short*)(ws + 8912896);
    short* Wvb = (short*)(ws + 9437184);
    short* Wob = (short*)(ws + 9961472);
    short* Qb  = (short*)(ws + 10485760);     // 8388608
    short* Kb  = (short*)(ws + 18874368);     // 8388608
    short* Vtb = (short*)(ws + 27262976);     // 8388608
    short* m1t = (short*)(ws + 35651584);     // 524288 (m1t|m2t contiguous)
    short* m2t = (short*)(ws + 36175872);     // 524288
    short* lm  = (short*)(ws + 36700160);     // 33554432
    short* lmr = (short*)(ws + 70254592);     // 33554432
    short* Ob  = (short*)(ws + 103809024);    // 8388608
    float* fro = (float*)(ws + 112197632);    // 128

    // casts (x + merged weights + merged masks)
    k_cast<<<2048, 256, 0, stream>>>(x, xb, (NB * NS * ND) / 8);
    k_castw<<<512, 256, 0, stream>>>(Wq, Wk, Wv, Wo, Wqb);
    k_tcast_mask<<<dim3(32, 8), 256, 0, stream>>>(mask1, mask2, m1t, m2t);

    // learnable mask + roll gather
    k_lm<<<dim3(32, 32, 4), 64, 0, stream>>>(m1t, m2t, lm);
    k_roll<<<8192, 256, 0, stream>>>(lm, roll, lmr);

    // fused QKV projection
    k_gemm_qkv<<<1536, 256, 0, stream>>>(xb, Wqb, Wkb, Wvb, bq, bk, bv, Qb, Kb, Vtb);

    // attention (needs zeroed fro accumulator)
    hipMemsetAsync(fro, 0, 128, stream);
    k_attn<<<512, 512, 0, stream>>>(Qb, Kb, Vtb, lmr, Ob, fro);

    // normalize + output projection
    k_scale<<<2048, 256, 0, stream>>>(Ob, fro);
    k_gemm_out<<<512, 256, 0, stream>>>(Ob, Wob, bo, out);
}

// Round 5
// 232.340 us; speedup vs baseline: 2.3238x; 1.0885x over previous
//
#include <hip/hip_runtime.h>
#include <hip/hip_bf16.h>

// Problem constants
#define NB 4
#define NS 2048
#define ND 512
#define NH 8
#define NM 4
#define NR 32
#define NHD 64

typedef short frag_ab __attribute__((ext_vector_type(8)));   // 8 bf16 (bits)
typedef float frag_cd __attribute__((ext_vector_type(4)));   // 4 f32

__device__ __forceinline__ float bf2f(short s) {
    union { unsigned u; float f; } c;
    c.u = ((unsigned)(unsigned short)s) << 16;
    return c.f;
}
__device__ __forceinline__ short f2bf(float f) {
    __hip_bfloat16 h = __float2bfloat16(f);
    union { __hip_bfloat16 h; short s; } c;
    c.h = h;
    return c.s;
}

// async global->LDS, 16B per lane. LDS dest must be base+lane*16 contiguous per wave.
__device__ __forceinline__ void gload16(const void* g, void* l) {
    __builtin_amdgcn_global_load_lds((const __attribute__((address_space(1))) unsigned int*)g,
                                     (__attribute__((address_space(3))) unsigned int*)l,
                                     16, 0, 0);
}

// Stage one 16B chunk of a [nrow][64] bf16 tile (128B rows, 8 chunks/row) with
// XOR swizzle cc ^= (row&7). LDS layout linear; source pre-swizzled (rule #21).
__device__ __forceinline__ void stage_tile(const short* src, size_t srcStride,
                                           char* lbase, int slot) {
    int o = slot * 16;
    int row = o >> 7;
    int cc = ((o >> 4) & 7) ^ (row & 7);
    gload16(src + (size_t)row * srcStride + cc * 8, lbase + o);
}

// Read a bf16x8 fragment from a swizzled [*][64] tile. cc_un = kk*4+g (unswizzled chunk).
__device__ __forceinline__ frag_ab lds_frag(const char* lbase, int row, int cc_un) {
    int cc = cc_un ^ (row & 7);
    return *(const frag_ab*)(lbase + row * 128 + cc * 16);
}

// ---------------- cast f32 -> bf16, 8 elems/thread ----------------
__global__ void __launch_bounds__(256) k_cast(const float* __restrict__ in,
                                              short* __restrict__ out, int n8) {
    int i = blockIdx.x * 256 + threadIdx.x;
    if (i >= n8) return;
    const float4* p = (const float4*)in + (size_t)i * 2;
    float4 a = p[0], b = p[1];
    frag_ab o;
    o[0] = f2bf(a.x); o[1] = f2bf(a.y); o[2] = f2bf(a.z); o[3] = f2bf(a.w);
    o[4] = f2bf(b.x); o[5] = f2bf(b.y); o[6] = f2bf(b.z); o[7] = f2bf(b.w);
    ((frag_ab*)out)[i] = o;
}

// ---------------- merged weight cast: Wq|Wk|Wv|Wo -> contiguous bf16 ----------------
__global__ void __launch_bounds__(256) k_castw(const float* __restrict__ Wq,
                                               const float* __restrict__ Wk,
                                               const float* __restrict__ Wv,
                                               const float* __restrict__ Wo,
                                               short* __restrict__ out) {
    int i = blockIdx.x * 256 + threadIdx.x;   // 0..131071 frags
    int which = i >> 15;                      // 32768 frags per weight
    int j = i & 32767;
    const float* src = which == 0 ? Wq : which == 1 ? Wk : which == 2 ? Wv : Wo;
    const float4* p = (const float4*)src + (size_t)j * 2;
    float4 a = p[0], b = p[1];
    frag_ab o;
    o[0] = f2bf(a.x); o[1] = f2bf(a.y); o[2] = f2bf(a.z); o[3] = f2bf(a.w);
    o[4] = f2bf(b.x); o[5] = f2bf(b.y); o[6] = f2bf(b.z); o[7] = f2bf(b.w);
    ((frag_ab*)out)[i] = o;
}

// ---------- transpose-cast masks: in[m][r][s] f32 -> out[m][s][r] bf16 (both masks) ----------
__global__ void __launch_bounds__(256) k_tcast_mask(const float* __restrict__ mask1,
                                                    const float* __restrict__ mask2,
                                                    short* __restrict__ m1t,
                                                    short* __restrict__ m2t) {
    int my = blockIdx.y;
    const float* in = my < 4 ? mask1 : mask2;
    short* out = my < 4 ? m1t : m2t;
    int m = my & 3;
    int s0 = blockIdx.x * 64, tid = threadIdx.x;
    __shared__ float tile[32][65];
    int c = tid & 63, r4 = tid >> 6;
#pragma unroll
    for (int p = 0; p < 8; ++p) {
        int r = p * 4 + r4;
        tile[r][c] = in[(m * 32 + r) * NS + s0 + c];
    }
    __syncthreads();
    int r = tid & 31, s4 = tid >> 5;
#pragma unroll
    for (int p = 0; p < 8; ++p) {
        int s = p * 8 + s4;
        out[(m * NS + s0 + s) * NR + r] = f2bf(tile[r][s]);
    }
}

// ---------------- fused lm + roll: lmr[m][s][t] = lm[m][s][roll[s][t]] ----------------
// Block: (m, 16 s-rows). Computes the lm tile with MFMA into an LDS row buffer,
// then gathers with roll indices and writes lmr coalesced. lm never hits global.
__global__ void __launch_bounds__(256) k_lmroll(const short* __restrict__ m1t,
                                                const short* __restrict__ m2t,
                                                const int* __restrict__ roll,
                                                short* __restrict__ lmr) {
    int n = blockIdx.x;              // 512: xcd keyed on m -> m2t slice L2-resident
    int xcd = n & 7, j = n >> 3;     // j 0..63
    int m = xcd >> 1;
    int st = (j << 1) | (xcd & 1);   // 0..127
    int s0 = st * 16;
    int tid = threadIdx.x, w = tid >> 6, lane = tid & 63;
    int lo = lane & 15, g = lane >> 4;

    __shared__ __align__(16) char rowbuf_[16 * 4160];   // 16 rows, 4160B stride (bank skew)

    frag_ab af = *(const frag_ab*)(m1t + (size_t)(m * NS + s0 + lo) * NR + g * 8);
    const short* m2b = m2t + (size_t)m * NS * NR;

    // each wave computes t-range [w*512, w*512+512)
    for (int tt = 0; tt < 8; ++tt) {
        int T0 = (w * 8 + tt) * 64;
        frag_cd sacc[4];
#pragma unroll
        for (int ni = 0; ni < 4; ++ni) {
            frag_ab bf = *(const frag_ab*)(m2b + (size_t)(T0 + ni * 16 + lo) * NR + g * 8);
            frag_cd z = {0.f, 0.f, 0.f, 0.f};
            sacc[ni] = __builtin_amdgcn_mfma_f32_16x16x32_bf16(af, bf, z, 0, 0, 0);
        }
        // store: row = g*4+r, col = T0+ni*16+lo  (imm-offset addressing)
        char* pw = rowbuf_ + g * (4 * 4160) + (size_t)(T0 + lo) * 2;
#pragma unroll
        for (int ni = 0; ni < 4; ++ni)
#pragma unroll
            for (int r = 0; r < 4; ++r)
                *(short*)(pw + r * 4160 + ni * 32) = f2bf(sacc[ni][r]);
    }
    __syncthreads();
    // gather + coalesced write
    int row = w * 4 + (lane >> 4);       // 0..15
    int tbase = (lane & 15) * 8;
    const short* rb = (const short*)(rowbuf_ + row * 4160);
    const int* rrow = roll + (size_t)(s0 + row) * NS;
    short* orow = lmr + ((size_t)(m * NS) + s0 + row) * NS;
#pragma unroll
    for (int c = 0; c < 16; ++c) {
        int t = c * 128 + tbase;
        int4 i0 = *(const int4*)(rrow + t);
        int4 i1 = *(const int4*)(rrow + t + 4);
        frag_ab o;
        o[0] = rb[i0.x]; o[1] = rb[i0.y]; o[2] = rb[i0.z]; o[3] = rb[i0.w];
        o[4] = rb[i1.x]; o[5] = rb[i1.y]; o[6] = rb[i1.z]; o[7] = rb[i1.w];
        *(frag_ab*)(orow + t) = o;
    }
}

// ---------------- fused QKV GEMM: 128x64 tile, BK=64, double-buffered LDS ----------
// Q output is pre-scaled by 0.125 (folds attention's 1/sqrt(HD) in for free).
__global__ void __launch_bounds__(256) k_gemm_qkv(const short* __restrict__ A,
                                                  const short* __restrict__ Wqb,
                                                  const short* __restrict__ Wkb,
                                                  const short* __restrict__ Wvb,
                                                  const float* __restrict__ bq,
                                                  const float* __restrict__ bk,
                                                  const float* __restrict__ bv,
                                                  short* __restrict__ Qb,
                                                  short* __restrict__ Kb,
                                                  short* __restrict__ Vtb) {
    int n = blockIdx.x;                 // 1536
    int rr = n >> 3;
    int Mb = (n & 7) * 8 + (rr & 7);    // XCD-contiguous A panels
    int Nb = rr >> 3;                   // 0..23
    int which = Nb >> 3;
    int bn0 = (Nb & 7) * 64;
    const short* W = which == 0 ? Wqb : which == 1 ? Wkb : Wvb;
    const float* bias = which == 0 ? bq : which == 1 ? bk : bv;
    short* out = which == 0 ? Qb : which == 1 ? Kb : Vtb;
    int bm0 = Mb * 128;
    int tid = threadIdx.x;
    int wid = tid >> 6, lane = tid & 63;
    int lo = lane & 15, g = lane >> 4;
    int wr = (wid >> 1) * 64, wc = (wid & 1) * 32;

    __shared__ __align__(16) char sm[2][24576];   // A 16KB @0, B 8KB @16384

    frag_cd acc[4][2];
#pragma unroll
    for (int mi = 0; mi < 4; ++mi)
#pragma unroll
        for (int ni = 0; ni < 2; ++ni) acc[mi][ni] = (frag_cd){0.f, 0.f, 0.f, 0.f};

    const short* Abase = A + (size_t)bm0 * ND;
    const short* Wbase = W + (size_t)bn0 * ND;

#pragma unroll
    for (int j = 0; j < 4; ++j) stage_tile(Abase, ND, sm[0], tid + j * 256);
#pragma unroll
    for (int j = 0; j < 2; ++j) stage_tile(Wbase, ND, sm[0] + 16384, tid + j * 256);
    __syncthreads();

    char* cb = sm[0];
    char* nb = sm[1];
    for (int kt = 0; kt < 8; ++kt) {
        if (kt < 7) {
            int k0 = (kt + 1) * 64;
#pragma unroll
            for (int j = 0; j < 4; ++j) stage_tile(Abase + k0, ND, nb, tid + j * 256);
#pragma unroll
            for (int j = 0; j < 2; ++j) stage_tile(Wbase + k0, ND, nb + 16384, tid + j * 256);
        }
#pragma unroll
        for (int kk = 0; kk < 2; ++kk) {
            frag_ab af[4], bf[2];
#pragma unroll
            for (int mi = 0; mi < 4; ++mi) af[mi] = lds_frag(cb, wr + mi * 16 + lo, kk * 4 + g);
#pragma unroll
            for (int ni = 0; ni < 2; ++ni) bf[ni] = lds_frag(cb + 16384, wc + ni * 16 + lo, kk * 4 + g);
#pragma unroll
            for (int mi = 0; mi < 4; ++mi)
#pragma unroll
                for (int ni = 0; ni < 2; ++ni)
                    acc[mi][ni] = __builtin_amdgcn_mfma_f32_16x16x32_bf16(af[mi], bf[ni], acc[mi][ni], 0, 0, 0);
        }
        __syncthreads();
        char* t = cb; cb = nb; nb = t;
    }

#pragma unroll
    for (int mi = 0; mi < 4; ++mi)
#pragma unroll
        for (int ni = 0; ni < 2; ++ni)
#pragma unroll
            for (int ri = 0; ri < 4; ++ri) {
                int row = bm0 + wr + mi * 16 + g * 4 + ri;
                int col = bn0 + wc + ni * 16 + lo;
                float v = acc[mi][ni][ri] + bias[col];
                if (which == 0) v *= 0.125f;   // fold 1/sqrt(HD)
                int b = row >> 11, s = row & 2047, h = col >> 6, d = col & 63;
                if (which < 2) {
                    out[(((size_t)(b * NH + h) * NS + s) << 6) + d] = f2bf(v);
                } else {
                    out[((size_t)(b * NH + h) * NHD + d) * NS + s] = f2bf(v);
                }
            }
}

// ---------------- output GEMM: C f32 = A(bf16) * W^T + bias, 128x64 tile ----------------
__global__ void __launch_bounds__(256) k_gemm_out(const short* __restrict__ A,
                                                  const short* __restrict__ W,
                                                  const float* __restrict__ bias,
                                                  float* __restrict__ out) {
    int n = blockIdx.x;                 // 512
    int rr = n >> 3;
    int Mb = (n & 7) * 8 + (rr & 7);
    int Nb = rr >> 3;                   // 0..7
    int bn0 = Nb * 64;
    int bm0 = Mb * 128;
    int tid = threadIdx.x;
    int wid = tid >> 6, lane = tid & 63;
    int lo = lane & 15, g = lane >> 4;
    int wr = (wid >> 1) * 64, wc = (wid & 1) * 32;

    __shared__ __align__(16) char sm[2][24576];

    frag_cd acc[4][2];
#pragma unroll
    for (int mi = 0; mi < 4; ++mi)
#pragma unroll
        for (int ni = 0; ni < 2; ++ni) acc[mi][ni] = (frag_cd){0.f, 0.f, 0.f, 0.f};

    const short* Abase = A + (size_t)bm0 * ND;
    const short* Wbase = W + (size_t)bn0 * ND;

#pragma unroll
    for (int j = 0; j < 4; ++j) stage_tile(Abase, ND, sm[0], tid + j * 256);
#pragma unroll
    for (int j = 0; j < 2; ++j) stage_tile(Wbase, ND, sm[0] + 16384, tid + j * 256);
    __syncthreads();

    char* cb = sm[0];
    char* nb = sm[1];
    for (int kt = 0; kt < 8; ++kt) {
        if (kt < 7) {
            int k0 = (kt + 1) * 64;
#pragma unroll
            for (int j = 0; j < 4; ++j) stage_tile(Abase + k0, ND, nb, tid + j * 256);
#pragma unroll
            for (int j = 0; j < 2; ++j) stage_tile(Wbase + k0, ND, nb + 16384, tid + j * 256);
        }
#pragma unroll
        for (int kk = 0; kk < 2; ++kk) {
            frag_ab af[4], bf[2];
#pragma unroll
            for (int mi = 0; mi < 4; ++mi) af[mi] = lds_frag(cb, wr + mi * 16 + lo, kk * 4 + g);
#pragma unroll
            for (int ni = 0; ni < 2; ++ni) bf[ni] = lds_frag(cb + 16384, wc + ni * 16 + lo, kk * 4 + g);
#pragma unroll
            for (int mi = 0; mi < 4; ++mi)
#pragma unroll
                for (int ni = 0; ni < 2; ++ni)
                    acc[mi][ni] = __builtin_amdgcn_mfma_f32_16x16x32_bf16(af[mi], bf[ni], acc[mi][ni], 0, 0, 0);
        }
        __syncthreads();
        char* t = cb; cb = nb; nb = t;
    }

#pragma unroll
    for (int mi = 0; mi < 4; ++mi)
#pragma unroll
        for (int ni = 0; ni < 2; ++ni)
#pragma unroll
            for (int ri = 0; ri < 4; ++ri) {
                int row = bm0 + wr + mi * 16 + g * 4 + ri;
                int col = bn0 + wc + ni * 16 + lo;
                out[(size_t)row * ND + col] = acc[mi][ni][ri] + bias[col];
            }
}

// ---------------- fused attention: O_unnorm = (QK^T * lm_rolled) @ V ; sumsq ----
// Q pre-scaled by 0.125. Scores stored f32 in padded wave-private LDS (no cvt at
// store, imm-offset addressing). 8 waves x 16 s-rows; K/V tiles double-buffered.
__global__ void __launch_bounds__(512, 4) k_attn(const short* __restrict__ Qb,
                                                 const short* __restrict__ Kb,
                                                 const short* __restrict__ Vt,
                                                 const short* __restrict__ lmr,
                                                 short* __restrict__ O,
                                                 float* __restrict__ fro) {
    int n = blockIdx.x;              // 0..511
    int xcd = n & 7;
    int idx = n >> 3;                // 0..63
    int b = idx & 3;
    int hh = (idx >> 2) & 1;
    int sbl = idx >> 3;              // 0..7
    int m = xcd >> 1;
    int sb = (xcd & 1) * 8 + sbl;    // 0..15
    int h = hh * 4 + m;
    int bh = b * NH + h;
    int tid = threadIdx.x;
    int w = tid >> 6, lane = tid & 63;
    int lo = lane & 15, g = lane >> 4;
    int srow = sb * 128 + w * 16;    // wave's 16-row s-base

    __shared__ __align__(16) char kv[2][16384];    // K tile 8KB @0, V^T tile 8KB @8192
    __shared__ __align__(16) char plds[8][4352];   // per-wave f32 P: 16 rows x 272B
    char* pbase = plds[w];

    const short* kbase = Kb + (size_t)bh * NS * NHD;
    const short* vbase = Vt + (size_t)bh * NHD * NS;
    const short* lmbase = lmr + ((size_t)m * NS + srow + lo) * NS;

    const short* qptr = Qb + ((size_t)bh * NS + srow + lo) * NHD + g * 8;
    frag_ab qf[2];
    qf[0] = *(const frag_ab*)(qptr);
    qf[1] = *(const frag_ab*)(qptr + 32);

    frag_cd acco[4];
#pragma unroll
    for (int ni = 0; ni < 4; ++ni) acco[ni] = (frag_cd){0.f, 0.f, 0.f, 0.f};
    float sumsq = 0.f;

    // prologue: stage t-block 0; prefetch lm frags for t-block 0
    stage_tile(kbase, NHD, kv[0], tid);
    stage_tile(vbase, NS, kv[0] + 8192, tid);
    frag_ab lc0 = *(const frag_ab*)(lmbase + g * 8);
    frag_ab lc1 = *(const frag_ab*)(lmbase + 32 + g * 8);
    __syncthreads();

    float* pw = (float*)(pbase + g * 1088 + lo * 4);        // write base (row g*4, col lo)
    const char* prb = pbase + lo * 272 + g * 32;            // read base (row lo, t g*8)

    char* cb = kv[0];
    char* nb = kv[1];
    for (int tb = 0; tb < 32; ++tb) {
        int t0 = tb * 64;
        frag_ab ln0 = lc0, ln1 = lc1;
        if (tb < 31) {
            stage_tile(kbase + (size_t)(t0 + 64) * NHD, NHD, nb, tid);
            stage_tile(vbase + (t0 + 64), NS, nb + 8192, tid);
            ln0 = *(const frag_ab*)(lmbase + t0 + 64 + g * 8);
            ln1 = *(const frag_ab*)(lmbase + t0 + 96 + g * 8);
        }
        // QK^T (Q pre-scaled by 1/8)
        frag_cd sacc[4];
#pragma unroll
        for (int ni = 0; ni < 4; ++ni) sacc[ni] = (frag_cd){0.f, 0.f, 0.f, 0.f};
#pragma unroll
        for (int kk = 0; kk < 2; ++kk)
#pragma unroll
            for (int ni = 0; ni < 4; ++ni)
                sacc[ni] = __builtin_amdgcn_mfma_f32_16x16x32_bf16(
                    qf[kk], lds_frag(cb, ni * 16 + lo, kk * 4 + g), sacc[ni], 0, 0, 0);
        // scores f32 -> wave-private padded LDS (pure imm-offset stores)
#pragma unroll
        for (int ni = 0; ni < 4; ++ni)
#pragma unroll
            for (int r = 0; r < 4; ++r)
                pw[r * 68 + ni * 16] = sacc[ni][r];
        // read back transposed (A-layout), multiply lm, accumulate sumsq, pack bf16
        frag_ab pf[2];
#pragma unroll
        for (int kk = 0; kk < 2; ++kk) {
            float4 s0 = *(const float4*)(prb + kk * 128);
            float4 s1 = *(const float4*)(prb + kk * 128 + 16);
            frag_ab lf = kk ? lc1 : lc0;
            float pv[8] = {s0.x, s0.y, s0.z, s0.w, s1.x, s1.y, s1.z, s1.w};
            frag_ab pp;
#pragma unroll
            for (int jj = 0; jj < 8; ++jj) {
                float p = pv[jj] * bf2f(lf[jj]);
                sumsq = fmaf(p, p, sumsq);
                pp[jj] = f2bf(p);
            }
            pf[kk] = pp;
        }
        // PV
#pragma unroll
        for (int ni = 0; ni < 4; ++ni)
#pragma unroll
            for (int kk = 0; kk < 2; ++kk)
                acco[ni] = __builtin_amdgcn_mfma_f32_16x16x32_bf16(
                    pf[kk], lds_frag(cb + 8192, ni * 16 + lo, kk * 4 + g), acco[ni], 0, 0, 0);
        lc0 = ln0;
        lc1 = ln1;
        __syncthreads();
        char* t = cb; cb = nb; nb = t;
    }
    // wave reduction of sumsq, one atomic per wave
#pragma unroll
    for (int off = 32; off; off >>= 1) sumsq += __shfl_xor(sumsq, off, 64);
    if (lane == 0) atomicAdd(&fro[bh], sumsq);
    // write unnormalized O (bf16) at [b, s, h*64+d]
#pragma unroll
    for (int ni = 0; ni < 4; ++ni)
#pragma unroll
        for (int r = 0; r < 4; ++r) {
            int s = srow + g * 4 + r;
            int d = ni * 16 + lo;
            O[((size_t)(b * NS + s)) * ND + h * NHD + d] = f2bf(acco[ni][r]);
        }
}

// ---------------- scale O in place by 1/(sqrt(fro[b,h])+eps) ----------------
__global__ void __launch_bounds__(256) k_scale(short* __restrict__ O,
                                               const float* __restrict__ fro) {
    int i = blockIdx.x * 256 + threadIdx.x;  // 8 bf16 per thread
    int i8 = i * 8;
    int col = i8 & 511;
    int row = i8 >> 9;
    float f = fro[(row >> 11) * NH + (col >> 6)];
    float sc = 1.f / (sqrtf(f) + 1e-8f);
    frag_ab v = ((frag_ab*)O)[i];
    frag_ab o;
#pragma unroll
    for (int j = 0; j < 8; ++j) o[j] = f2bf(bf2f(v[j]) * sc);
    ((frag_ab*)O)[i] = o;
}

extern "C" void kernel_launch(void* const* d_in, const int* in_sizes, int n_in,
                              void* d_out, int out_size, void* d_ws, size_t ws_size,
                              hipStream_t stream) {
    const float* x     = (const float*)d_in[0];
    const float* Wq    = (const float*)d_in[1];
    const float* bq    = (const float*)d_in[2];
    const float* Wk    = (const float*)d_in[3];
    const float* bk    = (const float*)d_in[4];
    const float* Wv    = (const float*)d_in[5];
    const float* bv    = (const float*)d_in[6];
    const float* mask1 = (const float*)d_in[7];
    const float* mask2 = (const float*)d_in[8];
    const float* Wo    = (const float*)d_in[9];
    const float* bo    = (const float*)d_in[10];
    const int*   roll  = (const int*)d_in[11];
    float* out = (float*)d_out;

    char* ws = (char*)d_ws;
    short* xb  = (short*)(ws + 0);            // 8388608
    short* Wqb = (short*)(ws + 8388608);      // 524288 (Wq|Wk|Wv|Wo contiguous)
    short* Wkb = (short*)(ws + 8912896);
    short* Wvb = (short*)(ws + 9437184);
    short* Wob = (short*)(ws + 9961472);
    short* Qb  = (short*)(ws + 10485760);     // 8388608
    short* Kb  = (short*)(ws + 18874368);     // 8388608
    short* Vtb = (short*)(ws + 27262976);     // 8388608
    short* m1t = (short*)(ws + 35651584);     // 524288
    short* m2t = (short*)(ws + 36175872);     // 524288
    short* lmr = (short*)(ws + 70254592);     // 33554432
    short* Ob  = (short*)(ws + 103809024);    // 8388608
    float* fro = (float*)(ws + 112197632);    // 128

    // casts (x + merged weights + merged masks)
    k_cast<<<2048, 256, 0, stream>>>(x, xb, (NB * NS * ND) / 8);
    k_castw<<<512, 256, 0, stream>>>(Wq, Wk, Wv, Wo, Wqb);
    k_tcast_mask<<<dim3(32, 8), 256, 0, stream>>>(mask1, mask2, m1t, m2t);

    // fused learnable-mask + roll gather (lm never materialized in HBM)
    k_lmroll<<<512, 256, 0, stream>>>(m1t, m2t, roll, lmr);

    // fused QKV projection (Q pre-scaled by 0.125)
    k_gemm_qkv<<<1536, 256, 0, stream>>>(xb, Wqb, Wkb, Wvb, bq, bk, bv, Qb, Kb, Vtb);

    // attention (needs zeroed fro accumulator)
    hipMemsetAsync(fro, 0, 128, stream);
    k_attn<<<512, 512, 0, stream>>>(Qb, Kb, Vtb, lmr, Ob, fro);

    // normalize + output projection
    k_scale<<<2048, 256, 0, stream>>>(Ob, fro);
    k_gemm_out<<<512, 256, 0, stream>>>(Ob, Wob, bo, out);
}